// Round 2
// baseline (151.838 us; speedup 1.0000x reference)
//
#include <hip/hip_runtime.h>
#include <hip/hip_bf16.h>

typedef short s16x8 __attribute__((ext_vector_type(8)));
typedef float f32x16 __attribute__((ext_vector_type(16)));

#define LOG2E 1.44269504088896f

__device__ __forceinline__ unsigned bfpack2(float lo, float hi) {
  unsigned a = (unsigned)__builtin_bit_cast(unsigned short, __float2bfloat16(lo));
  unsigned b = (unsigned)__builtin_bit_cast(unsigned short, __float2bfloat16(hi));
  return a | (b << 16);
}

union U4 { unsigned u[4]; uint4 q; s16x8 v; };

__device__ __forceinline__ void load_lds16(const char* g, char* l) {
  __builtin_amdgcn_global_load_lds(
      (const __attribute__((address_space(1))) unsigned*)g,
      (__attribute__((address_space(3))) unsigned*)l, 16, 0, 0);
}

// ---------------- prep: K,V f32 -> swizzled bf16 tile blocks in ws ----------
// Kb tile (bh,t): 16 KB. row r = kv (0..63), 256 B; 16B slot s holds d-chunk c = s ^ (r&7).
// Vt tile (bh,t): 16 KB. row d (0..127), 128 B; 16B slot s holds kv-chunk c = s ^ (d&7).
__global__ __launch_bounds__(256, 2)
void prep_kv(const float* __restrict__ Kg, const float* __restrict__ Vg,
             char* __restrict__ kb, char* __restrict__ vt) {
  constexpr int S = 2048, Dh = 128;
  const int g  = (int)blockIdx.x;          // bh*32 + t
  const int bh = g >> 5, t = g & 31;
  const size_t base = (size_t)bh * S * Dh + (size_t)(t << 6) * Dh;
  const int tid = (int)threadIdx.x;

  // ---- K: elementwise convert + chunk-swizzle ----
  {
    char* ktile = kb + ((size_t)g << 14);
    const int r  = tid >> 2;
    const int c4 = tid & 3;
    const float* krow = Kg + base + (size_t)r * Dh;
    #pragma unroll
    for (int p = 0; p < 4; ++p) {
      const int c = c4 + 4 * p;            // 16B chunk 0..15
      float4 a = *(const float4*)(krow + 8 * c);
      float4 b = *(const float4*)(krow + 8 * c + 4);
      U4 w;
      w.u[0] = bfpack2(a.x, a.y); w.u[1] = bfpack2(a.z, a.w);
      w.u[2] = bfpack2(b.x, b.y); w.u[3] = bfpack2(b.z, b.w);
      *(uint4*)(ktile + r * 256 + ((c ^ (r & 7)) << 4)) = w.q;
    }
  }
  // ---- V: transpose via LDS, convert, chunk-swizzle ----
  __shared__ float lds[64][132];
  {
    const int rv = tid >> 2, q4 = tid & 3;
    const float* vrow = Vg + base + (size_t)rv * Dh;
    #pragma unroll
    for (int p = 0; p < 8; ++p)
      *(float4*)(&lds[rv][q4 * 4 + p * 16]) = *(const float4*)(vrow + q4 * 4 + p * 16);
  }
  __syncthreads();
  {
    char* vtile = vt + ((size_t)g << 14);
    const int d = tid >> 1, h = tid & 1;
    #pragma unroll
    for (int cc = 0; cc < 4; ++cc) {
      const int c = 4 * h + cc;            // kv chunk 0..7
      U4 w;
      #pragma unroll
      for (int u = 0; u < 4; ++u)
        w.u[u] = bfpack2(lds[8 * c + 2 * u][d], lds[8 * c + 2 * u + 1][d]);
      *(uint4*)(vtile + d * 128 + ((c ^ (d & 7)) << 4)) = w.q;
    }
  }
}

// ---------------- main: QBLK=64 (2 waves), KVBLK=64, dbuf + counted vmcnt ----
__global__ __launch_bounds__(128, 2)
void attn_alibi(const float* __restrict__ Qg, float* __restrict__ Og,
                const char* __restrict__ kb, const char* __restrict__ vt) {
  constexpr int S = 2048, Dh = 128;
  const int lid  = (int)blockIdx.x;
  const int xcd  = lid & 7;
  const int slot = lid >> 3;
  const int bh   = xcd + 8 * (slot >> 5);  // 4 heads per XCD -> K/V L2-resident
  const int qt   = 31 - (slot & 31);       // heavy-first
  const int head = bh & 15;

  const int tid  = (int)threadIdx.x;
  const int wq   = tid >> 6, lane = tid & 63, l31 = lane & 31, h5 = lane >> 5;
  const int q0   = qt << 6;
  const int iq   = q0 + 32 * wq + l31;

  const float c1     = 0.08838834764831845f * LOG2E;
  const float slope2 = exp2f(-0.5f * (float)(head + 1)) * LOG2E;

  const char* kb_bh = kb + ((size_t)bh << 19);
  const char* vt_bh = vt + ((size_t)bh << 19);

  __shared__ __align__(16) char smem[65536]; // K dbuf 2x16K @0, V dbuf 2x16K @32768

  // Q fragments: elem i <-> d = 16*ks + 8*h5 + i
  s16x8 qf[8];
  {
    const float* qrow = Qg + (size_t)bh * S * Dh + (size_t)iq * Dh;
    #pragma unroll
    for (int ks = 0; ks < 8; ++ks) {
      const float* p = qrow + 16 * ks + 8 * h5;
      float4 a = *(const float4*)p;
      float4 b = *(const float4*)(p + 4);
      U4 w;
      w.u[0] = bfpack2(a.x, a.y); w.u[1] = bfpack2(a.z, a.w);
      w.u[2] = bfpack2(b.x, b.y); w.u[3] = bfpack2(b.z, b.w);
      qf[ks] = w.v;
    }
  }

  f32x16 oacc[4];
  #pragma unroll
  for (int dt = 0; dt < 4; ++dt)
    #pragma unroll
    for (int r = 0; r < 16; ++r) oacc[dt][r] = 0.0f;

  float m2 = -1e30f, lsum = 0.0f;

  const int wo = wq << 13;  // wave's 8 KB half of each 16 KB tile

#define STAGE(buf, tt) do {                                                   \
    const char* ks_ = kb_bh + ((size_t)(tt) << 14) + wo + lane * 16;          \
    const char* vs_ = vt_bh + ((size_t)(tt) << 14) + wo + lane * 16;          \
    char* kd_ = smem + ((buf) << 14) + wo;                                    \
    char* vd_ = smem + 32768 + ((buf) << 14) + wo;                            \
    _Pragma("unroll")                                                         \
    for (int i_ = 0; i_ < 8; ++i_) {                                          \
      load_lds16(ks_ + i_ * 1024, kd_ + i_ * 1024);                           \
      load_lds16(vs_ + i_ * 1024, vd_ + i_ * 1024);                           \
    }                                                                         \
  } while (0)

  const int nt = qt + 1;   // causal: tiles 0..qt, last is the diagonal tile
  STAGE(0, 0);

  for (int t = 0; t < nt; ++t) {
    const int cur = t & 1;
    const int kv0 = t << 6;
    char* kbuf = smem + (cur << 14);
    char* vbuf = smem + 32768 + (cur << 14);

    if (t + 1 < nt) {
      STAGE(cur ^ 1, t + 1);
      asm volatile("s_waitcnt vmcnt(16)" ::: "memory"); // own t-loads landed
    } else {
      asm volatile("s_waitcnt vmcnt(0)" ::: "memory");
    }
    __builtin_amdgcn_s_barrier();           // buf[cur] ready on all waves
    asm volatile("" ::: "memory");

    // ---- S^T = K · Q^T ----
    f32x16 sc[2];
    #pragma unroll
    for (int kt = 0; kt < 2; ++kt) {
      #pragma unroll
      for (int r = 0; r < 16; ++r) sc[kt][r] = 0.0f;
      const int row = kt * 32 + l31;
      const char* kr = kbuf + row * 256;
      const int sw = row & 7;
      #pragma unroll
      for (int ks = 0; ks < 8; ++ks) {
        s16x8 a = *(const s16x8*)(kr + (((2 * ks + h5) ^ sw) << 4));
        sc[kt] = __builtin_amdgcn_mfma_f32_32x32x16_bf16(a, qf[ks], sc[kt], 0, 0, 0);
      }
    }

    // ---- online softmax (lane-local q), defer-max THR=8 ----
    float mloc = -1e30f;
    #pragma unroll
    for (int kt = 0; kt < 2; ++kt) {
      #pragma unroll
      for (int r = 0; r < 16; ++r) {
        const float pat = (float)((r & 3) + 8 * (r >> 2) + 4 * h5 + 32 * kt);
        const float dj  = (float)(kv0 - iq) + pat;      // j - i
        float v = fmaf(sc[kt][r], c1, slope2 * dj);
        v = (dj > 0.0f) ? -1e30f : v;
        sc[kt][r] = v;
        mloc = fmaxf(mloc, v);
      }
    }
    mloc = fmaxf(mloc, __shfl_xor(mloc, 32));
    if (!__all(mloc <= m2 + 8.0f)) {        // rescale only when max grew
      const float mnew = fmaxf(m2, mloc);
      const float corr = exp2f(m2 - mnew);
      m2 = mnew;
      lsum *= corr;
      #pragma unroll
      for (int dt = 0; dt < 4; ++dt)
        #pragma unroll
        for (int r = 0; r < 16; ++r) oacc[dt][r] *= corr;
    }
    float ps = 0.0f;
    #pragma unroll
    for (int kt = 0; kt < 2; ++kt)
      #pragma unroll
      for (int r = 0; r < 16; ++r) {
        const float pv = exp2f(sc[kt][r] - m2);
        sc[kt][r] = pv;
        ps += pv;
      }
    ps += __shfl_xor(ps, 32);
    lsum += ps;

    // ---- pack P^T ----
    unsigned pk[2][4][2];
    #pragma unroll
    for (int kt = 0; kt < 2; ++kt)
      #pragma unroll
      for (int rg = 0; rg < 4; ++rg) {
        pk[kt][rg][0] = bfpack2(sc[kt][4 * rg + 0], sc[kt][4 * rg + 1]);
        pk[kt][rg][1] = bfpack2(sc[kt][4 * rg + 2], sc[kt][4 * rg + 3]);
      }

    // ---- O^T += V^T · P^T ----
    #pragma unroll
    for (int ks = 0; ks < 4; ++ks) {
      const int kt = ks >> 1;
      const int x  = 2 * (ks & 1);
      const unsigned own0 = h5 ? pk[kt][x + 1][0] : pk[kt][x][0];
      const unsigned own1 = h5 ? pk[kt][x + 1][1] : pk[kt][x][1];
      const unsigned snd0 = h5 ? pk[kt][x][0]     : pk[kt][x + 1][0];
      const unsigned snd1 = h5 ? pk[kt][x][1]     : pk[kt][x + 1][1];
      const unsigned sh0 = (unsigned)__shfl_xor((int)snd0, 32);
      const unsigned sh1 = (unsigned)__shfl_xor((int)snd1, 32);
      U4 bfr;
      bfr.u[0] = h5 ? sh0 : own0;
      bfr.u[1] = h5 ? sh1 : own1;
      bfr.u[2] = h5 ? own0 : sh0;
      bfr.u[3] = h5 ? own1 : sh1;
      const int cv = 2 * ks + h5;           // kv 16B chunk
      #pragma unroll
      for (int dt = 0; dt < 4; ++dt) {
        const int d = 32 * dt + l31;
        s16x8 a = *(const s16x8*)(vbuf + d * 128 + (((cv) ^ (d & 7)) << 4));
        oacc[dt] = __builtin_amdgcn_mfma_f32_32x32x16_bf16(a, bfr.v, oacc[dt], 0, 0, 0);
      }
    }

    asm volatile("" ::: "memory");
    __builtin_amdgcn_s_barrier();           // all waves done reading buf[cur]
  }
#undef STAGE

  // ---- epilogue ----
  const float rl = 1.0f / lsum;
  float* orow = Og + (size_t)bh * S * Dh + (size_t)iq * Dh;
  #pragma unroll
  for (int dt = 0; dt < 4; ++dt)
    #pragma unroll
    for (int rg = 0; rg < 4; ++rg) {
      float4 v;
      v.x = oacc[dt][4 * rg + 0] * rl;
      v.y = oacc[dt][4 * rg + 1] * rl;
      v.z = oacc[dt][4 * rg + 2] * rl;
      v.w = oacc[dt][4 * rg + 3] * rl;
      *(float4*)(orow + 32 * dt + 8 * rg + 4 * h5) = v;
    }
}

extern "C" void kernel_launch(void* const* d_in, const int* in_sizes, int n_in,
                              void* d_out, int out_size, void* d_ws, size_t ws_size,
                              hipStream_t stream) {
  (void)in_sizes; (void)n_in; (void)out_size; (void)ws_size;
  const float* q = (const float*)d_in[0];
  const float* k = (const float*)d_in[1];
  const float* v = (const float*)d_in[2];
  float* o = (float*)d_out;
  char* kbuf = (char*)d_ws;                  // 16 MB swizzled bf16 K tiles
  char* vbuf = kbuf + (32u << 19);           // 16 MB swizzled bf16 V^T tiles
  prep_kv<<<dim3(1024), dim3(256), 0, stream>>>(k, v, kbuf, vbuf);
  attn_alibi<<<dim3(1024), dim3(128), 0, stream>>>(q, o, kbuf, vbuf);
}

// Round 3
// 150.930 us; speedup vs baseline: 1.0060x; 1.0060x over previous
//
#include <hip/hip_runtime.h>
#include <hip/hip_bf16.h>

typedef short s16x8 __attribute__((ext_vector_type(8)));
typedef float f32x16 __attribute__((ext_vector_type(16)));

#define LOG2E 1.44269504088896f

__device__ __forceinline__ unsigned bfpack2(float lo, float hi) {
  unsigned a = (unsigned)__builtin_bit_cast(unsigned short, __float2bfloat16(lo));
  unsigned b = (unsigned)__builtin_bit_cast(unsigned short, __float2bfloat16(hi));
  return a | (b << 16);
}

union U4 { unsigned u[4]; uint4 q; s16x8 v; };

__device__ __forceinline__ void load_lds16(const char* g, char* l) {
  __builtin_amdgcn_global_load_lds(
      (const __attribute__((address_space(1))) unsigned*)g,
      (__attribute__((address_space(3))) unsigned*)l, 16, 0, 0);
}

// ---------------- prep: K,V f32 -> swizzled bf16 KVBLK=32 tiles ----------
// K tile (bh,t): 8 KB; row r = kv (0..31), 256 B; slot s holds d-chunk c = s ^ (r&7).
// V tile (bh,t): 8 KB; row rho = d>>1 (0..63), 128 B; slot s holds chi = s ^ (rho&7),
//   chunk chi = 4e+cv: bf16 kv = 8cv..8cv+7 of column d = 2rho+e.
__global__ __launch_bounds__(128)
void prep_kv(const float* __restrict__ Kg, const float* __restrict__ Vg,
             char* __restrict__ kb, char* __restrict__ vt) {
  constexpr int S = 2048, Dh = 128;
  const int g  = (int)blockIdx.x;          // bh*64 + t
  const int bh = g >> 6, t = g & 63;
  const size_t base = (size_t)bh * S * Dh + (size_t)(t << 5) * Dh;
  const int tid = (int)threadIdx.x;

  // ---- K: convert + chunk-swizzle ----
  {
    char* ktile = kb + ((size_t)g << 13);
    const int r  = tid >> 2;
    const int c4 = tid & 3;
    const float* krow = Kg + base + (size_t)r * Dh;
    #pragma unroll
    for (int p = 0; p < 4; ++p) {
      const int c = c4 + 4 * p;            // 16B chunk 0..15
      float4 a = *(const float4*)(krow + 8 * c);
      float4 b = *(const float4*)(krow + 8 * c + 4);
      U4 w;
      w.u[0] = bfpack2(a.x, a.y); w.u[1] = bfpack2(a.z, a.w);
      w.u[2] = bfpack2(b.x, b.y); w.u[3] = bfpack2(b.z, b.w);
      *(uint4*)(ktile + r * 256 + ((c ^ (r & 7)) << 4)) = w.q;
    }
  }
  // ---- V: transpose via LDS, paired-row layout, chunk-swizzle ----
  __shared__ float lds[32][132];
  {
    const int rv = tid >> 2, q4 = tid & 3;
    const float* vrow = Vg + base + (size_t)rv * Dh;
    #pragma unroll
    for (int p = 0; p < 8; ++p)
      *(float4*)(&lds[rv][q4 * 32 + 4 * p]) = *(const float4*)(vrow + q4 * 32 + 4 * p);
  }
  __syncthreads();
  {
    char* vtile = vt + ((size_t)g << 13);
    #pragma unroll
    for (int p = 0; p < 4; ++p) {
      const int cid = tid + 128 * p;       // 0..511
      const int rho = cid >> 3, s = cid & 7;
      const int chi = s ^ (rho & 7);
      const int e = chi >> 2, cv = chi & 3;
      const int d = 2 * rho + e;
      U4 w;
      #pragma unroll
      for (int u = 0; u < 4; ++u)
        w.u[u] = bfpack2(lds[8 * cv + 2 * u][d], lds[8 * cv + 2 * u + 1][d]);
      *(uint4*)(vtile + rho * 128 + s * 16) = w.q;
    }
  }
}

// ---------------- main: QBLK=64 (2 waves interleaved), KVBLK=32 ----------
__global__ __launch_bounds__(128, 3)
void attn_alibi(const float* __restrict__ Qg, float* __restrict__ Og,
                const char* __restrict__ kb, const char* __restrict__ vt) {
  constexpr int S = 2048, Dh = 128;
  const int lid  = (int)blockIdx.x;
  const int xcd  = lid & 7;
  const int slot = lid >> 3;
  const int bh   = xcd + 8 * (slot >> 5);  // 4 heads per XCD
  const int qt   = 31 - (slot & 31);       // heavy-first
  const int head = bh & 15;

  const int tid  = (int)threadIdx.x;
  const int wq   = tid >> 6, lane = tid & 63, l31 = lane & 31, h5 = lane >> 5;
  const int q0   = qt << 6;
  const int iq   = q0 + 2 * l31 + wq;      // interleaved: both waves share diagonal

  const float c1     = 0.08838834764831845f * LOG2E;
  const float slope2 = exp2f(-0.5f * (float)(head + 1)) * LOG2E;

  const char* kb_bh = kb + ((size_t)bh << 19);
  const char* vt_bh = vt + ((size_t)bh << 19);

  __shared__ __align__(16) char smem[32768]; // K dbuf 2x8K @0, V dbuf 2x8K @16384

  // Q fragments: elem i <-> d = 16*ks + 8*h5 + i
  s16x8 qf[8];
  {
    const float* qrow = Qg + (size_t)bh * S * Dh + (size_t)iq * Dh;
    #pragma unroll
    for (int ks = 0; ks < 8; ++ks) {
      const float* p = qrow + 16 * ks + 8 * h5;
      float4 a = *(const float4*)p;
      float4 b = *(const float4*)(p + 4);
      U4 w;
      w.u[0] = bfpack2(a.x, a.y); w.u[1] = bfpack2(a.z, a.w);
      w.u[2] = bfpack2(b.x, b.y); w.u[3] = bfpack2(b.z, b.w);
      qf[ks] = w.v;
    }
  }

  // per-lane alibi constants: cpat[r] = slope2 * pat_r
  float cpat[16];
  #pragma unroll
  for (int r = 0; r < 16; ++r)
    cpat[r] = slope2 * (float)((r & 3) + 8 * (r >> 2) + 4 * h5);

  f32x16 oacc[4];
  #pragma unroll
  for (int dt = 0; dt < 4; ++dt)
    #pragma unroll
    for (int r = 0; r < 16; ++r) oacc[dt][r] = 0.0f;

  float m2 = -3.0e38f, lsum = 0.0f;

  const int vro = (l31 >> 1) * 128;   // V row byte offset (rho within dt-block)
  const int swv = (l31 >> 1) & 7;
  const int e4  = (l31 & 1) << 2;

#define STAGE(buf, tt) do {                                                   \
    const char* ks_ = kb_bh + ((size_t)(tt) << 13) + wq * 4096 + lane * 16;   \
    const char* vs_ = vt_bh + ((size_t)(tt) << 13) + wq * 4096 + lane * 16;   \
    char* kd_ = smem + ((buf) << 13) + wq * 4096;                             \
    char* vd_ = smem + 16384 + ((buf) << 13) + wq * 4096;                     \
    _Pragma("unroll")                                                         \
    for (int i_ = 0; i_ < 4; ++i_) {                                          \
      load_lds16(ks_ + i_ * 1024, kd_ + i_ * 1024);                           \
      load_lds16(vs_ + i_ * 1024, vd_ + i_ * 1024);                           \
    }                                                                         \
  } while (0)

  const int nt = 2 * qt + 2;
  STAGE(0, 0);

  for (int t = 0; t < nt; ++t) {
    __syncthreads();                    // drains own loads, then barrier
    if (t + 1 < nt) STAGE((t + 1) & 1, t + 1);
    const char* kbuf = smem + ((t & 1) << 13);
    const char* vbuf = smem + 16384 + ((t & 1) << 13);
    const int kv0 = t << 5;

    // ---- S^T = K · Q^T ----
    f32x16 sc;
    #pragma unroll
    for (int r = 0; r < 16; ++r) sc[r] = 0.0f;
    const char* kr = kbuf + l31 * 256;
    const int sw = l31 & 7;
    __builtin_amdgcn_s_setprio(1);
    #pragma unroll
    for (int ks = 0; ks < 8; ++ks) {
      s16x8 a = *(const s16x8*)(kr + (((2 * ks + h5) ^ sw) << 4));
      sc = __builtin_amdgcn_mfma_f32_32x32x16_bf16(a, qf[ks], sc, 0, 0, 0);
    }
    __builtin_amdgcn_s_setprio(0);

    // ---- bias + (last-2-tiles-only) causal mask; b>0 <=> j>i exactly ----
    const float sb = slope2 * (float)(kv0 - iq);
    float mloc = -3.0e38f;
    if (t + 2 < nt) {
      #pragma unroll
      for (int r = 0; r < 16; ++r) {
        float v = fmaf(sc[r], c1, sb + cpat[r]);
        sc[r] = v;
        mloc = fmaxf(mloc, v);
      }
    } else {
      #pragma unroll
      for (int r = 0; r < 16; ++r) {
        const float b = sb + cpat[r];
        float v = fmaf(sc[r], c1, b);
        v = (b > 0.0f) ? -3.0e38f : v;
        sc[r] = v;
        mloc = fmaxf(mloc, v);
      }
    }
    mloc = fmaxf(mloc, __shfl_xor(mloc, 32));
    if (!__all(mloc <= m2 + 8.0f)) {    // defer-max THR=8
      const float mnew = fmaxf(m2, mloc);
      const float corr = __builtin_amdgcn_exp2f(m2 - mnew);
      m2 = mnew;
      lsum *= corr;
      #pragma unroll
      for (int dt = 0; dt < 4; ++dt)
        #pragma unroll
        for (int r = 0; r < 16; ++r) oacc[dt][r] *= corr;
    }
    float ps = 0.0f;
    #pragma unroll
    for (int r = 0; r < 16; ++r) {
      const float p = __builtin_amdgcn_exp2f(sc[r] - m2);
      sc[r] = p;
      ps += p;
    }
    lsum += ps;                         // half-partial; combined in epilogue

    // ---- pack P^T ----
    unsigned pk[4][2];
    #pragma unroll
    for (int rg = 0; rg < 4; ++rg) {
      pk[rg][0] = bfpack2(sc[4 * rg + 0], sc[4 * rg + 1]);
      pk[rg][1] = bfpack2(sc[4 * rg + 2], sc[4 * rg + 3]);
    }

    // ---- O^T += V^T · P^T (permlane32_swap builds both frag halves) ----
    #pragma unroll
    for (int ks = 0; ks < 2; ++ks) {
      unsigned a0 = pk[2 * ks][0], b0 = pk[2 * ks + 1][0];
      unsigned a1 = pk[2 * ks][1], b1 = pk[2 * ks + 1][1];
      asm("v_permlane32_swap_b32 %0, %1" : "+v"(a0), "+v"(b0));
      asm("v_permlane32_swap_b32 %0, %1" : "+v"(a1), "+v"(b1));
      U4 bf;
      bf.u[0] = a0; bf.u[1] = a1; bf.u[2] = b0; bf.u[3] = b1;
      __builtin_amdgcn_s_setprio(1);
      #pragma unroll
      for (int dt = 0; dt < 4; ++dt) {
        s16x8 a = *(const s16x8*)(vbuf + dt * 2048 + vro +
                                  (((e4 + 2 * ks + h5) ^ swv) << 4));
        oacc[dt] = __builtin_amdgcn_mfma_f32_32x32x16_bf16(a, bf.v, oacc[dt], 0, 0, 0);
      }
      __builtin_amdgcn_s_setprio(0);
    }
  }
#undef STAGE

  // ---- epilogue ----
  lsum += __shfl_xor(lsum, 32);
  const float rl = 1.0f / lsum;
  float* orow = Og + (size_t)bh * S * Dh + (size_t)iq * Dh;
  #pragma unroll
  for (int dt = 0; dt < 4; ++dt)
    #pragma unroll
    for (int rg = 0; rg < 4; ++rg) {
      float4 v;
      v.x = oacc[dt][4 * rg + 0] * rl;
      v.y = oacc[dt][4 * rg + 1] * rl;
      v.z = oacc[dt][4 * rg + 2] * rl;
      v.w = oacc[dt][4 * rg + 3] * rl;
      *(float4*)(orow + 32 * dt + 8 * rg + 4 * h5) = v;
    }
}

extern "C" void kernel_launch(void* const* d_in, const int* in_sizes, int n_in,
                              void* d_out, int out_size, void* d_ws, size_t ws_size,
                              hipStream_t stream) {
  (void)in_sizes; (void)n_in; (void)out_size; (void)ws_size;
  const float* q = (const float*)d_in[0];
  const float* k = (const float*)d_in[1];
  const float* v = (const float*)d_in[2];
  float* o = (float*)d_out;
  char* kbuf = (char*)d_ws;                  // 16 MB swizzled bf16 K tiles
  char* vbuf = kbuf + ((size_t)32 << 19);    // 16 MB swizzled bf16 V^T tiles
  prep_kv<<<dim3(2048), dim3(128), 0, stream>>>(k, v, kbuf, vbuf);
  attn_alibi<<<dim3(1024), dim3(128), 0, stream>>>(q, o, kbuf, vbuf);
}

// Round 7
// 137.427 us; speedup vs baseline: 1.1049x; 1.0983x over previous
//
#include <hip/hip_runtime.h>
#include <hip/hip_bf16.h>

typedef short s16x8 __attribute__((ext_vector_type(8)));
typedef float f32x16 __attribute__((ext_vector_type(16)));

#define LOG2E 1.44269504088896f

__device__ __forceinline__ unsigned bfpack2(float lo, float hi) {
  unsigned a = (unsigned)__builtin_bit_cast(unsigned short, __float2bfloat16(lo));
  unsigned b = (unsigned)__builtin_bit_cast(unsigned short, __float2bfloat16(hi));
  return a | (b << 16);
}

union U4 { unsigned u[4]; uint4 q; s16x8 v; };

__device__ __forceinline__ void load_lds16(const char* g, char* l) {
  __builtin_amdgcn_global_load_lds(
      (const __attribute__((address_space(1))) unsigned*)g,
      (__attribute__((address_space(3))) unsigned*)l, 16, 0, 0);
}

// ---------------- prep: K,V f32 -> swizzled bf16 KVBLK=32 tiles (R3-proven) --
__global__ __launch_bounds__(128)
void prep_kv(const float* __restrict__ Kg, const float* __restrict__ Vg,
             char* __restrict__ kb, char* __restrict__ vt) {
  constexpr int S = 2048, Dh = 128;
  const int g  = (int)blockIdx.x;          // bh*64 + t
  const int bh = g >> 6, t = g & 63;
  const size_t base = (size_t)bh * S * Dh + (size_t)(t << 5) * Dh;
  const int tid = (int)threadIdx.x;

  {
    char* ktile = kb + ((size_t)g << 13);
    const int r  = tid >> 2;
    const int c4 = tid & 3;
    const float* krow = Kg + base + (size_t)r * Dh;
    #pragma unroll
    for (int p = 0; p < 4; ++p) {
      const int c = c4 + 4 * p;
      float4 a = *(const float4*)(krow + 8 * c);
      float4 b = *(const float4*)(krow + 8 * c + 4);
      U4 w;
      w.u[0] = bfpack2(a.x, a.y); w.u[1] = bfpack2(a.z, a.w);
      w.u[2] = bfpack2(b.x, b.y); w.u[3] = bfpack2(b.z, b.w);
      *(uint4*)(ktile + r * 256 + ((c ^ (r & 7)) << 4)) = w.q;
    }
  }
  __shared__ float lds[32][132];
  {
    const int rv = tid >> 2, q4 = tid & 3;
    const float* vrow = Vg + base + (size_t)rv * Dh;
    #pragma unroll
    for (int p = 0; p < 8; ++p)
      *(float4*)(&lds[rv][q4 * 32 + 4 * p]) = *(const float4*)(vrow + q4 * 32 + 4 * p);
  }
  __syncthreads();
  {
    char* vtile = vt + ((size_t)g << 13);
    #pragma unroll
    for (int p = 0; p < 4; ++p) {
      const int cid = tid + 128 * p;
      const int rho = cid >> 3, s = cid & 7;
      const int chi = s ^ (rho & 7);
      const int e = chi >> 2, cv = chi & 3;
      const int d = 2 * rho + e;
      U4 w;
      #pragma unroll
      for (int u = 0; u < 4; ++u)
        w.u[u] = bfpack2(lds[8 * cv + 2 * u][d], lds[8 * cv + 2 * u + 1][d]);
      *(uint4*)(vtile + rho * 128 + s * 16) = w.q;
    }
  }
}

// ---- main: R3 inner loop; paired q-tiles (qt, 31-qt) -> uniform 66 steps ----
// FIX vs R6: epilogue lsum reduction via __shfl_xor (the a==b inline-asm
// permlane could coalesce both operands into ONE VGPR -> self-swap -> lsum=0
// on rows whose other half is empty -> 1/0 = inf).
__global__ __launch_bounds__(128, 3)
void attn_alibi(const float* __restrict__ Qg, float* __restrict__ Og,
                const char* __restrict__ kb, const char* __restrict__ vt) {
  constexpr int S = 2048, Dh = 128;
  const int lid  = (int)blockIdx.x;        // 0..511
  const int xcd  = lid & 7;
  const int u    = lid >> 3;               // 0..63
  const int bh   = xcd + 8 * (u >> 4);     // 4 heads per XCD
  const int pr   = u & 15;                 // pair id 0..15
  const int head = bh & 15;

  const int tid  = (int)threadIdx.x;
  const int wq   = tid >> 6, lane = tid & 63, l31 = lane & 31, h5 = lane >> 5;

  const float c1     = 0.08838834764831845f * LOG2E;
  const float slope2 = exp2f(-0.5f * (float)(head + 1)) * LOG2E;

  const char* kb_bh = kb + ((size_t)bh << 19);
  const char* vt_bh = vt + ((size_t)bh << 19);

  __shared__ __align__(16) char smem[32768];

  float cpat[16];
  #pragma unroll
  for (int r = 0; r < 16; ++r)
    cpat[r] = slope2 * (float)((r & 3) + 8 * (r >> 2) + 4 * h5);

  const int vro = (l31 >> 1) * 128;
  const int swv = (l31 >> 1) & 7;
  const int e4  = (l31 & 1) << 2;

#define STAGE(buf, tt) do {                                                   \
    const char* ks_ = kb_bh + ((size_t)(tt) << 13) + wq * 4096 + lane * 16;   \
    const char* vs_ = vt_bh + ((size_t)(tt) << 13) + wq * 4096 + lane * 16;   \
    char* kd_ = smem + ((buf) << 13) + wq * 4096;                             \
    char* vd_ = smem + 16384 + ((buf) << 13) + wq * 4096;                     \
    _Pragma("unroll")                                                         \
    for (int i_ = 0; i_ < 4; ++i_) {                                          \
      load_lds16(ks_ + i_ * 1024, kd_ + i_ * 1024);                           \
      load_lds16(vs_ + i_ * 1024, vd_ + i_ * 1024);                           \
    }                                                                         \
  } while (0)

  for (int ph = 0; ph < 2; ++ph) {
    const int qt = ph ? (31 - pr) : pr;
    const int q0 = qt << 6;
    const int iq = q0 + 2 * l31 + wq;      // interleaved rows within q-tile

    s16x8 qf[8];
    {
      const float* qrow = Qg + (size_t)bh * S * Dh + (size_t)iq * Dh;
      #pragma unroll
      for (int ks = 0; ks < 8; ++ks) {
        const float* p = qrow + 16 * ks + 8 * h5;
        float4 a = *(const float4*)p;
        float4 b = *(const float4*)(p + 4);
        U4 w;
        w.u[0] = bfpack2(a.x, a.y); w.u[1] = bfpack2(a.z, a.w);
        w.u[2] = bfpack2(b.x, b.y); w.u[3] = bfpack2(b.z, b.w);
        qf[ks] = w.v;
      }
    }

    f32x16 oacc[4];
    #pragma unroll
    for (int dt = 0; dt < 4; ++dt)
      #pragma unroll
      for (int r = 0; r < 16; ++r) oacc[dt][r] = 0.0f;

    float m2 = -3.0e38f, lsum = 0.0f;

    const int nt = 2 * qt + 2;             // even: last tile uses buf 1
    STAGE(0, 0);                           // phase-safe: writes buf 0

    for (int t = 0; t < nt; ++t) {
      __syncthreads();
      if (t + 1 < nt) STAGE((t + 1) & 1, t + 1);
      const char* kbuf = smem + ((t & 1) << 13);
      const char* vbuf = smem + 16384 + ((t & 1) << 13);
      const int kv0 = t << 5;

      // ---- S^T = K · Q^T ----
      f32x16 sc;
      #pragma unroll
      for (int r = 0; r < 16; ++r) sc[r] = 0.0f;
      const char* kr = kbuf + l31 * 256;
      const int sw = l31 & 7;
      __builtin_amdgcn_s_setprio(1);
      #pragma unroll
      for (int ks = 0; ks < 8; ++ks) {
        s16x8 a = *(const s16x8*)(kr + (((2 * ks + h5) ^ sw) << 4));
        sc = __builtin_amdgcn_mfma_f32_32x32x16_bf16(a, qf[ks], sc, 0, 0, 0);
      }
      __builtin_amdgcn_s_setprio(0);

      // ---- bias + (last-2-tiles-only) causal mask ----
      const float sb = slope2 * (float)(kv0 - iq);
      float mloc = -3.0e38f;
      if (t + 2 < nt) {
        #pragma unroll
        for (int r = 0; r < 16; ++r) {
          float v = fmaf(sc[r], c1, sb + cpat[r]);
          sc[r] = v;
          mloc = fmaxf(mloc, v);
        }
      } else {
        #pragma unroll
        for (int r = 0; r < 16; ++r) {
          const float b = sb + cpat[r];
          float v = fmaf(sc[r], c1, b);
          v = (b > 0.0f) ? -3.0e38f : v;
          sc[r] = v;
          mloc = fmaxf(mloc, v);
        }
      }
      mloc = fmaxf(mloc, __shfl_xor(mloc, 32));
      if (!__all(mloc <= m2 + 8.0f)) {     // defer-max THR=8
        const float mnew = fmaxf(m2, mloc);
        const float corr = __builtin_amdgcn_exp2f(m2 - mnew);
        m2 = mnew;
        lsum *= corr;
        #pragma unroll
        for (int dt = 0; dt < 4; ++dt)
          #pragma unroll
          for (int r = 0; r < 16; ++r) oacc[dt][r] *= corr;
      }
      float ps = 0.0f;
      #pragma unroll
      for (int r = 0; r < 16; ++r) {
        const float p = __builtin_amdgcn_exp2f(sc[r] - m2);
        sc[r] = p;
        ps += p;
      }
      lsum += ps;                          // half-partial; combined in epilogue

      // ---- pack P^T ----
      unsigned pk[4][2];
      #pragma unroll
      for (int rg = 0; rg < 4; ++rg) {
        pk[rg][0] = bfpack2(sc[4 * rg + 0], sc[4 * rg + 1]);
        pk[rg][1] = bfpack2(sc[4 * rg + 2], sc[4 * rg + 3]);
      }

      // ---- O^T += V^T · P^T ----
      #pragma unroll
      for (int ks = 0; ks < 2; ++ks) {
        unsigned a0 = pk[2 * ks][0], b0 = pk[2 * ks + 1][0];
        unsigned a1 = pk[2 * ks][1], b1 = pk[2 * ks + 1][1];
        asm("v_permlane32_swap_b32 %0, %1" : "+v"(a0), "+v"(b0));
        asm("v_permlane32_swap_b32 %0, %1" : "+v"(a1), "+v"(b1));
        U4 bf;
        bf.u[0] = a0; bf.u[1] = a1; bf.u[2] = b0; bf.u[3] = b1;
        __builtin_amdgcn_s_setprio(1);
        #pragma unroll
        for (int dt = 0; dt < 4; ++dt) {
          s16x8 a = *(const s16x8*)(vbuf + dt * 2048 + vro +
                                    (((e4 + 2 * ks + h5) ^ swv) << 4));
          oacc[dt] = __builtin_amdgcn_mfma_f32_32x32x16_bf16(a, bf.v, oacc[dt], 0, 0, 0);
        }
        __builtin_amdgcn_s_setprio(0);
      }
    }

    // ---- epilogue: cross-half combine via shfl (regalloc-safe) ----
    lsum += __shfl_xor(lsum, 32);
    const float rl = 1.0f / lsum;
    float* orow = Og + (size_t)bh * S * Dh + (size_t)iq * Dh;
    #pragma unroll
    for (int dt = 0; dt < 4; ++dt)
      #pragma unroll
      for (int rg = 0; rg < 4; ++rg) {
        float4 v;
        v.x = oacc[dt][4 * rg + 0] * rl;
        v.y = oacc[dt][4 * rg + 1] * rl;
        v.z = oacc[dt][4 * rg + 2] * rl;
        v.w = oacc[dt][4 * rg + 3] * rl;
        *(float4*)(orow + 32 * dt + 8 * rg + 4 * h5) = v;
      }
  }
#undef STAGE
}

extern "C" void kernel_launch(void* const* d_in, const int* in_sizes, int n_in,
                              void* d_out, int out_size, void* d_ws, size_t ws_size,
                              hipStream_t stream) {
  (void)in_sizes; (void)n_in; (void)out_size; (void)ws_size;
  const float* q = (const float*)d_in[0];
  const float* k = (const float*)d_in[1];
  const float* v = (const float*)d_in[2];
  float* o = (float*)d_out;
  char* kbuf = (char*)d_ws;
  char* vbuf = kbuf + ((size_t)32 << 19);
  prep_kv<<<dim3(2048), dim3(128), 0, stream>>>(k, v, kbuf, vbuf);
  attn_alibi<<<dim3(512), dim3(128), 0, stream>>>(q, o, kbuf, vbuf);
}

// Round 8
// 95.093 us; speedup vs baseline: 1.5967x; 1.4452x over previous
//
#include <hip/hip_runtime.h>
#include <hip/hip_bf16.h>

typedef short s16x8 __attribute__((ext_vector_type(8)));
typedef float f32x16 __attribute__((ext_vector_type(16)));

#define LOG2E 1.44269504088896f

__device__ __forceinline__ unsigned bfpack2(float lo, float hi) {
  unsigned a = (unsigned)__builtin_bit_cast(unsigned short, __float2bfloat16(lo));
  unsigned b = (unsigned)__builtin_bit_cast(unsigned short, __float2bfloat16(hi));
  return a | (b << 16);
}

union U4 { unsigned u[4]; uint4 q; s16x8 v; };

// ---- prep: K,V f32 -> fragment-major bf16 tiles (16KB per (bh, kv-tile)) ----
// tile g = bh*64+t at tiles + g*16384:
//   K-frag ks (0..7) at ks*1024:      [lane*16] = K[32t+(lane&31)][16ks+8*(lane>>5) +0..7]
//   V-frag g'=ks*4+dt (0..7) at 8192+g'*1024: [lane*16] = bf16 pairs u=0..3 of
//      (V[32t+8cv+2u][d], V[32t+8cv+2u+1][d]),  cv=2ks+(lane>>5), d=32dt+(lane&31)
__global__ __launch_bounds__(128)
void prep_kv(const float* __restrict__ Kg, const float* __restrict__ Vg,
             char* __restrict__ tiles) {
  constexpr int S = 2048, Dh = 128;
  const int g  = (int)blockIdx.x;          // bh*64 + t
  const int bh = g >> 6, t = g & 63;
  const size_t base = (size_t)bh * S * Dh + (size_t)(t << 5) * Dh;
  char* out = tiles + ((size_t)g << 14);
  const int tid = (int)threadIdx.x;
  const int lane = tid & 63, half = tid >> 6;
  const int l31 = lane & 31, h5 = lane >> 5;

  // K fragments
  {
    const float* krow = Kg + base + (size_t)l31 * Dh;
    #pragma unroll
    for (int i = 0; i < 4; ++i) {
      const int ks = half * 4 + i;
      const float* p = krow + 16 * ks + 8 * h5;
      float4 a = *(const float4*)p;
      float4 b = *(const float4*)(p + 4);
      U4 w;
      w.u[0] = bfpack2(a.x, a.y); w.u[1] = bfpack2(a.z, a.w);
      w.u[2] = bfpack2(b.x, b.y); w.u[3] = bfpack2(b.z, b.w);
      *(uint4*)(out + ks * 1024 + lane * 16) = w.q;
    }
  }
  // V fragments via LDS transpose
  __shared__ float lds[32][132];
  {
    const int rv = tid >> 2, q4 = tid & 3;
    const float* vrow = Vg + base + (size_t)rv * Dh;
    #pragma unroll
    for (int p = 0; p < 8; ++p)
      *(float4*)(&lds[rv][q4 * 4 + p * 16]) = *(const float4*)(vrow + q4 * 4 + p * 16);
  }
  __syncthreads();
  {
    #pragma unroll
    for (int i = 0; i < 4; ++i) {
      const int gp = half * 4 + i;         // 0..7
      const int ks = gp >> 2, dt = gp & 3;
      const int cv = 2 * ks + h5, d = 32 * dt + l31;
      U4 w;
      #pragma unroll
      for (int u = 0; u < 4; ++u)
        w.u[u] = bfpack2(lds[8 * cv + 2 * u][d], lds[8 * cv + 2 * u + 1][d]);
      *(uint4*)(out + 8192 + gp * 1024 + lane * 16) = w.q;
    }
  }
}

// ---- main: 2-wave blocks, pair (qt,63-qt), kv-parity split, no hot barriers --
__global__ __launch_bounds__(128, 2)
void attn_alibi(const float* __restrict__ Qg, float* __restrict__ Og,
                const char* __restrict__ tiles) {
  constexpr int S = 2048, Dh = 128;
  const int lid  = (int)blockIdx.x;        // 0..1023
  const int xcd  = lid & 7;
  const int u    = lid >> 3;               // 0..127
  const int bh   = xcd + 8 * (u >> 5);     // 4 heads per XCD
  const int pr   = u & 31;                 // pair id 0..31
  const int head = bh & 15;

  const int tid  = (int)threadIdx.x;
  const int wq   = tid >> 6;               // kv parity of this wave
  const int lane = tid & 63, l31 = lane & 31, h5 = lane >> 5;

  const float c1     = 0.08838834764831845f * LOG2E;
  const float slope2 = exp2f(-0.5f * (float)(head + 1)) * LOG2E;

  const char* tb = tiles + (((size_t)bh << 6) << 14);

  float cpat[16];
  #pragma unroll
  for (int r = 0; r < 16; ++r)
    cpat[r] = slope2 * (float)((r & 3) + 8 * (r >> 2) + 4 * h5);

  __shared__ float olds[4][64][17];        // partner O halves (scalar-written)
  __shared__ float mlds[2][2][32];         // per-wave (m, l)

  for (int ph = 0; ph < 2; ++ph) {
    const int qt = ph ? (63 - pr) : pr;    // 32-row q-tile index 0..63
    const int iq = (qt << 5) + l31;

    // Q fragments (both waves load the same rows)
    s16x8 qf[8];
    {
      const float* qrow = Qg + (size_t)bh * S * Dh + (size_t)iq * Dh;
      #pragma unroll
      for (int ks = 0; ks < 8; ++ks) {
        const float* p = qrow + 16 * ks + 8 * h5;
        float4 a = *(const float4*)p;
        float4 b = *(const float4*)(p + 4);
        U4 w;
        w.u[0] = bfpack2(a.x, a.y); w.u[1] = bfpack2(a.z, a.w);
        w.u[2] = bfpack2(b.x, b.y); w.u[3] = bfpack2(b.z, b.w);
        qf[ks] = w.v;
      }
    }

    f32x16 oacc[4];
    #pragma unroll
    for (int dt = 0; dt < 4; ++dt)
      #pragma unroll
      for (int r = 0; r < 16; ++r) oacc[dt][r] = 0.0f;
    float m2 = -3.0e38f, lsum = 0.0f;

    const int nt = qt + 1;
    for (int t = wq; t < nt; t += 2) {     // this wave's parity subset
      const char* kb = tb + ((size_t)t << 14) + lane * 16;
      s16x8 kf[8], vf[8];
      #pragma unroll
      for (int ks = 0; ks < 8; ++ks)
        kf[ks] = *(const s16x8*)(kb + ks * 1024);
      #pragma unroll
      for (int gp = 0; gp < 8; ++gp)
        vf[gp] = *(const s16x8*)(kb + 8192 + gp * 1024);

      // ---- S^T = K · Q^T ----
      f32x16 sc;
      #pragma unroll
      for (int r = 0; r < 16; ++r) sc[r] = 0.0f;
      __builtin_amdgcn_s_setprio(1);
      #pragma unroll
      for (int ks = 0; ks < 8; ++ks)
        sc = __builtin_amdgcn_mfma_f32_32x32x16_bf16(kf[ks], qf[ks], sc, 0, 0, 0);
      __builtin_amdgcn_s_setprio(0);

      // ---- bias + causal mask on diagonal tile only ----
      const float sb = slope2 * (float)((t << 5) - iq);
      float mloc = -3.0e38f;
      if (t != qt) {
        #pragma unroll
        for (int r = 0; r < 16; ++r) {
          float v = fmaf(sc[r], c1, sb + cpat[r]);
          sc[r] = v;
          mloc = fmaxf(mloc, v);
        }
      } else {
        #pragma unroll
        for (int r = 0; r < 16; ++r) {
          const float b = sb + cpat[r];
          float v = fmaf(sc[r], c1, b);
          v = (b > 0.0f) ? -3.0e38f : v;   // sign-exact j>i
          sc[r] = v;
          mloc = fmaxf(mloc, v);
        }
      }
      mloc = fmaxf(mloc, __shfl_xor(mloc, 32));
      if (!__all(mloc <= m2 + 8.0f)) {     // defer-max THR=8
        const float mnew = fmaxf(m2, mloc);
        const float corr = __builtin_amdgcn_exp2f(m2 - mnew);
        m2 = mnew;
        lsum *= corr;
        #pragma unroll
        for (int dt = 0; dt < 4; ++dt)
          #pragma unroll
          for (int r = 0; r < 16; ++r) oacc[dt][r] *= corr;
      }
      float ps = 0.0f;
      #pragma unroll
      for (int r = 0; r < 16; ++r) {
        const float p = __builtin_amdgcn_exp2f(sc[r] - m2);
        sc[r] = p;
        ps += p;
      }
      lsum += ps;                          // half-partial

      // ---- pack P^T ----
      unsigned pk[4][2];
      #pragma unroll
      for (int rg = 0; rg < 4; ++rg) {
        pk[rg][0] = bfpack2(sc[4 * rg + 0], sc[4 * rg + 1]);
        pk[rg][1] = bfpack2(sc[4 * rg + 2], sc[4 * rg + 3]);
      }

      // ---- O^T += V^T · P^T ----
      #pragma unroll
      for (int ks = 0; ks < 2; ++ks) {
        unsigned a0 = pk[2 * ks][0], b0 = pk[2 * ks + 1][0];
        unsigned a1 = pk[2 * ks][1], b1 = pk[2 * ks + 1][1];
        asm("v_permlane32_swap_b32 %0, %1" : "+v"(a0), "+v"(b0));
        asm("v_permlane32_swap_b32 %0, %1" : "+v"(a1), "+v"(b1));
        U4 bf;
        bf.u[0] = a0; bf.u[1] = a1; bf.u[2] = b0; bf.u[3] = b1;
        __builtin_amdgcn_s_setprio(1);
        #pragma unroll
        for (int dt = 0; dt < 4; ++dt)
          oacc[dt] = __builtin_amdgcn_mfma_f32_32x32x16_bf16(
              vf[4 * ks + dt], bf.v, oacc[dt], 0, 0, 0);
        __builtin_amdgcn_s_setprio(0);
      }
    }

    // ---- cross-wave merge: wave w finalizes d-half w ----
    lsum += __shfl_xor(lsum, 32);          // combine h5 halves (regalloc-safe)
    #pragma unroll
    for (int dtL = 0; dtL < 2; ++dtL) {
      const int dt = 2 * (1 - wq) + dtL;   // write the half the PARTNER finalizes
      #pragma unroll
      for (int r = 0; r < 16; ++r) olds[dt][lane][r] = oacc[dt][r];
    }
    mlds[wq][0][l31] = m2;                 // uniform across h5
    mlds[wq][1][l31] = lsum;
    __syncthreads();
    {
      const float pm = mlds[1 - wq][0][l31];
      const float pl = mlds[1 - wq][1][l31];
      const float ms = fmaxf(m2, pm);
      const float so = __builtin_amdgcn_exp2f(m2 - ms);
      const float sp = __builtin_amdgcn_exp2f(pm - ms);
      const float rl = 1.0f / (lsum * so + pl * sp);
      float* orow = Og + (size_t)bh * S * Dh + (size_t)iq * Dh;
      #pragma unroll
      for (int dtL = 0; dtL < 2; ++dtL) {
        const int dt = 2 * wq + dtL;       // this wave's final d-half
        #pragma unroll
        for (int rg = 0; rg < 4; ++rg) {
          float4 v;
          v.x = (oacc[dt][4 * rg + 0] * so + olds[dt][lane][4 * rg + 0] * sp) * rl;
          v.y = (oacc[dt][4 * rg + 1] * so + olds[dt][lane][4 * rg + 1] * sp) * rl;
          v.z = (oacc[dt][4 * rg + 2] * so + olds[dt][lane][4 * rg + 2] * sp) * rl;
          v.w = (oacc[dt][4 * rg + 3] * so + olds[dt][lane][4 * rg + 3] * sp) * rl;
          *(float4*)(orow + 32 * dt + 8 * rg + 4 * h5) = v;
        }
      }
    }
    __syncthreads();                       // LDS reuse guard before next phase
  }
}

extern "C" void kernel_launch(void* const* d_in, const int* in_sizes, int n_in,
                              void* d_out, int out_size, void* d_ws, size_t ws_size,
                              hipStream_t stream) {
  (void)in_sizes; (void)n_in; (void)out_size; (void)ws_size;
  const float* q = (const float*)d_in[0];
  const float* k = (const float*)d_in[1];
  const float* v = (const float*)d_in[2];
  float* o = (float*)d_out;
  char* tiles = (char*)d_ws;               // 32 MiB fragment-major bf16 tiles
  prep_kv<<<dim3(2048), dim3(128), 0, stream>>>(k, v, tiles);
  attn_alibi<<<dim3(1024), dim3(128), 0, stream>>>(q, o, tiles);
}